// Round 8
// baseline (169.480 us; speedup 1.0000x reference)
//
#include <hip/hip_runtime.h>
#include <math.h>

#define D2R      0.017453292519943295f
#define TAU_LN2  0.17328679513998632f   /* tau*ln2: soft = TAU_LN2*(mz - log2 S) */
#define KR       45690.73f              /* 2R * K, K = (1/tau)*log2(e) */
#define KRP      71763.68f              /* 2R*(pi/2) * K */
#define MBIG     1.0e30f
#define DMASK    2.0e30f
#define NBINS    125
#define P        8
#define CH       1024
#define NG_MAX   1152
#define NBLK     1024

__device__ __forceinline__ float fexp2(float x) { return __builtin_amdgcn_exp2f(x); }
__device__ __forceinline__ float rfl(float x) {
  return __int_as_float(__builtin_amdgcn_readfirstlane(__float_as_int(x)));
}

// ---- ws layout (bytes) ----
// 0 nitems | 4 ngroups | 8 done-ticket | 12 pad
// 16      grec  int2[NG_MAX]   {pcount, cnt}
// 9232    irec  int4[4608]     {bin, pb|(pcount<<20), cnt, (gi<<2)|c}
// 82960   ptrig float4[8192]   {cosLat, sinLat, cosLon, sinLon} bin-compacted
// 214032  pm float[NG_MAX*32]  scaled partial min   [group][chunk][pred]
// 361488  ps float[NG_MAX*32]  scaled partial sum
#define W_NI(w)    ((int*)(w))
#define W_NGR(w)   ((int*)((char*)(w) + 4))
#define W_DONE(w)  ((int*)((char*)(w) + 8))
#define W_GREC(w)  ((int2*)((char*)(w) + 16))
#define W_IREC(w)  ((int4*)((char*)(w) + 9232))
#define W_PTRIG(w) ((float4*)((char*)(w) + 82960))
#define W_PM(w)    ((float*)((char*)(w) + 214032))
#define W_PS(w)    ((float*)((char*)(w) + 361488))

// ---------- kernel 1: grouping (single block) ----------
__global__ __launch_bounds__(1024) void group_kernel(
    const float2* __restrict__ preds, const int* __restrict__ xv,
    const int* __restrict__ bin_counts, void* __restrict__ w, int B) {
  __shared__ int h[NBINS], cur[NBINS], pb[NBINS], gb[NBINS], ib[NBINS], cc[NBINS];
  const int tid = threadIdx.x;

  if (tid < NBINS) { h[tid] = 0; cc[tid] = bin_counts[tid]; }
  __syncthreads();

  for (int i = tid; i < B; i += 1024) {
    int bin = xv[3 * i] * 25 + xv[3 * i + 1] * 5 + xv[3 * i + 2];
    atomicAdd(&h[bin], 1);
  }
  __syncthreads();

  if (tid == 0) {
    int base = 0, g = 0, it = 0;
    for (int b = 0; b < NBINS; ++b) {          // serial, LDS-only
      pb[b] = base; gb[b] = g; ib[b] = it;
      int ngb  = (h[b] + 7) >> 3;
      int nchb = (cc[b] + CH - 1) >> 10;
      base += h[b]; g += ngb; it += ngb * nchb;
    }
    *W_NI(w) = it; *W_NGR(w) = g; *W_DONE(w) = 0;
  }
  __syncthreads();

  if (tid < NBINS) {
    cur[tid] = 0;
    const int b = tid, hb = h[b], cb_ = cc[b];
    const int ng = (hb + 7) >> 3, nch = (cb_ + CH - 1) >> 10;
    const int g0 = gb[b], i0 = ib[b], p0 = pb[b];
    for (int g = 0; g < ng; ++g) {
      int pc = min(P, hb - g * P);
      W_GREC(w)[g0 + g] = make_int2(pc, cb_);
      for (int c = 0; c < nch; ++c)
        W_IREC(w)[i0 + g * nch + c] =
            make_int4(b, (p0 + g * P) | (pc << 20), cb_, ((g0 + g) << 2) | c);
    }
  }
  __syncthreads();

  for (int i = tid; i < B; i += 1024) {
    int bin = xv[3 * i] * 25 + xv[3 * i + 1] * 5 + xv[3 * i + 2];
    int pos = pb[bin] + atomicAdd(&cur[bin], 1);
    float2 p = preds[i];
    float sA, cA, sO, cO;
    __sincosf(p.y * D2R, &sA, &cA);
    __sincosf(p.x * D2R, &sO, &cO);
    W_PTRIG(w)[pos] = make_float4(cA, sA, cO, sO);
  }
}

// ---------- kernel 2: persistent main + last-block merge/finalize ----------
__global__ __launch_bounds__(256) void main_kernel(
    const float2* __restrict__ bc, void* __restrict__ w, int M,
    float* __restrict__ out) {
  const int bid = blockIdx.x, tid = threadIdx.x;
  const int ni = *W_NI(w);

  __shared__ float redm[4][P], reds[4][P];
  __shared__ int sticket;

  for (int i = bid; i < ni; i += NBLK) {
    const int4 rec = W_IREC(w)[i];
    const int bin = rec.x, cnt = rec.z;
    const int pbb = rec.y & 0xFFFFF, pq = rec.y >> 20;
    const int gi = rec.w >> 2, c = rec.w & 3;

    float cA[P], sA[P], cO[P], sO[P];
#pragma unroll
    for (int p = 0; p < P; ++p) {
      float4 t = W_PTRIG(w)[pbb + min(p, pq - 1)];
      cA[p] = rfl(t.x); sA[p] = rfl(t.y); cO[p] = rfl(t.z); sO[p] = rfl(t.w);
    }

    const float2* __restrict__ cbp = bc + (size_t)bin * (size_t)M;
    const int c0 = c << 10;
    const int cend = min(cnt, c0 + CH);
    const int nst = (cend - c0 + 255) >> 8;

    float m[P], s[P];
#pragma unroll
    for (int p = 0; p < P; ++p) { m[p] = MBIG; s[p] = 0.0f; }

    float2 curc = cbp[min(c0 + tid, cend - 1)];
    for (int st = 0; st < nst; ++st) {
      const int idx = c0 + (st << 8) + tid;
      float2 nxt = cbp[min(idx + 256, cend - 1)];   // 1-deep prefetch
      float sla, cla, slo, clo;
      __sincosf(curc.y * D2R, &sla, &cla);
      __sincosf(curc.x * D2R, &slo, &clo);
      const float nh_sla = -0.5f * sla, h_cla = 0.5f * cla;
      const bool valid = idx < cend;
#pragma unroll
      for (int p = 0; p < P; ++p) {
        float cdlon = fmaf(cO[p], clo, sO[p] * slo);
        // a = 0.5 - 0.5*sA*sla - 0.5*cA*cla*cdlon  (folded haversine)
        float a = fmaf(-(cA[p] * h_cla), cdlon, fmaf(sA[p], nh_sla, 0.5f));
        a = fminf(fmaxf(a, 0.0f), 1.0f);
        float x = sqrtf(a);
        float pl = fmaf(x, -0.0012624911f, 0.0066700901f);  // A&S asin poly
        pl = fmaf(x, pl, -0.0170881256f);
        pl = fmaf(x, pl,  0.0308918810f);
        pl = fmaf(x, pl, -0.0501743046f);
        pl = fmaf(x, pl,  0.0889789874f);
        pl = fmaf(x, pl, -0.2145988016f);
        pl = fmaf(x, pl,  1.5707963050f);
        float wq = sqrtf(1.0f - x);
        float dz = fmaf(-KR, wq * pl, KRP);   // K-scaled distance
        dz = valid ? dz : DMASK;
        float mn = fminf(m[p], dz);
        s[p] = fmaf(s[p], fexp2(mn - m[p]), fexp2(mn - dz));
        m[p] = mn;
      }
      curc = nxt;
    }

    // wave reduce: min, one rescale, sum (scaled space)
#pragma unroll
    for (int p = 0; p < P; ++p) {
      float mw = m[p];
#pragma unroll
      for (int o = 32; o; o >>= 1) mw = fminf(mw, __shfl_xor(mw, o));
      float sp = s[p] * fexp2(mw - m[p]);
#pragma unroll
      for (int o = 32; o; o >>= 1) sp += __shfl_xor(sp, o);
      m[p] = mw; s[p] = sp;
    }

    const int wave = tid >> 6;
    if ((tid & 63) == 0) {
#pragma unroll
      for (int p = 0; p < P; ++p) { redm[wave][p] = m[p]; reds[wave][p] = s[p]; }
    }
    __syncthreads();
    if (tid < P) {
      float M4 = fminf(fminf(redm[0][tid], redm[1][tid]),
                       fminf(redm[2][tid], redm[3][tid]));
      float S4 = reds[0][tid] * fexp2(M4 - redm[0][tid])
               + reds[1][tid] * fexp2(M4 - redm[1][tid])
               + reds[2][tid] * fexp2(M4 - redm[2][tid])
               + reds[3][tid] * fexp2(M4 - redm[3][tid]);
      W_PM(w)[gi * 32 + (c << 3) + tid] = M4;
      W_PS(w)[gi * 32 + (c << 3) + tid] = S4;
    }
    __syncthreads();   // protect redm/reds reuse next item
  }

  // ---- completion ticket (device-scope release+acquire) ----
  if (tid == 0) {
    __threadfence();
    sticket = __hip_atomic_fetch_add(W_DONE(w), 1, __ATOMIC_ACQ_REL,
                                     __HIP_MEMORY_SCOPE_AGENT);
  }
  __syncthreads();

  if (sticket == NBLK - 1) {           // last block: merge + finalize
    const int ng = *W_NGR(w);
    float accf = 0.0f; int accn = 0;
    for (int t = tid; t < ng * P; t += 256) {
      const int gi = t >> 3, p = t & 7;
      const int2 gr = W_GREC(w)[gi];
      const int pc = gr.x, cnt = gr.y;
      if (cnt > 0) {
        const int nch = (cnt + CH - 1) >> 10;
        float mz = W_PM(w)[gi * 32 + p];
        float sz = W_PS(w)[gi * 32 + p];
        for (int c = 1; c < nch; ++c) {
          float mo = W_PM(w)[gi * 32 + (c << 3) + p];
          float so = W_PS(w)[gi * 32 + (c << 3) + p];
          float mn = fminf(mz, mo);
          sz = fmaf(sz, fexp2(mn - mz), so * fexp2(mn - mo));
          mz = mn;
        }
        if (p < pc) accf += TAU_LN2 * (mz - __log2f(sz));  // un-scale
        if (p == 0) accn += pc;
      }
    }
#pragma unroll
    for (int o = 32; o; o >>= 1) {
      accf += __shfl_xor(accf, o);
      accn += __shfl_xor(accn, o);
    }
    __shared__ float mf[4];
    __shared__ int   mi[4];
    const int wave = tid >> 6;
    if ((tid & 63) == 0) { mf[wave] = accf; mi[wave] = accn; }
    __syncthreads();
    if (tid == 0) {
      float f = mf[0] + mf[1] + mf[2] + mf[3];
      int   n = mi[0] + mi[1] + mi[2] + mi[3];
      if (n < 1) n = 1;
      out[0] = f / (float)n;
    }
  }
}

extern "C" void kernel_launch(void* const* d_in, const int* in_sizes, int n_in,
                              void* d_out, int out_size, void* d_ws, size_t ws_size,
                              hipStream_t stream) {
  const float2* preds      = (const float2*)d_in[0];  // (B,2) [lon,lat] deg
  const float2* bin_coords = (const float2*)d_in[1];  // (125,M,2) [lon,lat] deg
  const int*    x_vals     = (const int*)d_in[2];     // (B,3)
  const int*    bin_counts = (const int*)d_in[3];     // (125,)
  float*        out        = (float*)d_out;

  const int B = in_sizes[0] / 2;
  const int M = (in_sizes[1] / 2) / NBINS;            // 4096

  group_kernel<<<1, 1024, 0, stream>>>(preds, x_vals, bin_counts, d_ws, B);
  main_kernel<<<NBLK, 256, 0, stream>>>(bin_coords, d_ws, M, out);
}